// Round 10
// baseline (5429.764 us; speedup 1.0000x reference)
//
#include <hip/hip_runtime.h>
#include <math.h>

// ---------------------------------------------------------------------------
// ODERGRU pipeline for MI355X.
//  K1: einsum -> h1 (3200,96,29)
//  K2: conv1d 96->96 k5 + bias -> h2 + BN partials
//  K3: BN1 reduce   K5: BN2 reduce  (f64 tree)
//  K4: conv1d 96->16 k5 (BN1+lrelu on load) -> h3 + BN2 partials
//  K6: OAS + Cholesky -> x_d, x_o
//  K0: pack ODE/GRU weights f32 -> f16 fragments (MFMA lane order)
//  K7: 4 blocks x 1 wave x 16 rows. SWAPPED MFMA: A=W (streamed, 2-stage reg
//      prefetch), B=X^T (LDS, read ONCE per layer). C-layout => b64 activation
//      writes, b128 B reads, all XOR-swizzled. Zero barriers (single wave).
//      d-gates stay f32 VALU.
// ---------------------------------------------------------------------------

#define BB 64
#define NIMG 3200

typedef _Float16 f16;
typedef _Float16 f16x8 __attribute__((ext_vector_type(8)));
typedef float f32x4 __attribute__((ext_vector_type(4)));

__device__ __forceinline__ float fsigm(float x) {
  return __fdividef(1.f, 1.f + __expf(-x));
}
__device__ __forceinline__ float ftanh(float x) {
  return 1.f - __fdividef(2.f, __expf(2.f * x) + 1.f);
}

// pk region offsets (u32 units)
#define OFF_W0  0
#define OFF_W1  20480
#define OFF_W2  53248
#define OFF_W3  86016
#define OFF_GRZ 104448
#define OFF_GNX 135168
#define OFF_GNH 143360
#define PK2_TOT 151552

// ------------------------------ K1: filterbank ------------------------------
__global__ __launch_bounds__(256) void k1_fb(const float* __restrict__ x,
                                             const float* __restrict__ fw,
                                             const float* __restrict__ st,
                                             float* __restrict__ h1) {
  __shared__ __align__(16) float ws[129 * 32];
  __shared__ __align__(16) float xs[129 * 32];
  const int tid = threadIdx.x;
  const int n = blockIdx.x;
  const float* xp = x + (size_t)n * 11223;

  for (int i = tid; i < 4128; i += 256) ws[i] = fw[i] * st[i];

  float acc[4][4];
#pragma unroll
  for (int i = 0; i < 4; ++i)
#pragma unroll
    for (int j = 0; j < 4; ++j) acc[i][j] = 0.f;

  const int c = tid / 64;
  const int rem = tid % 64;
  const int m0 = (rem / 8) * 4;
  const int t0 = (rem % 8) * 4;

  for (int fc = 0; fc < 3; ++fc) {
    __syncthreads();
    for (int i = tid; i < 3741; i += 256) {
      int cc = i / 1247;
      int r = i - cc * 1247;
      int f = r / 29;
      int t = r - f * 29;
      xs[(cc * 43 + f) * 32 + t] = xp[cc * 3741 + (fc * 43 + f) * 29 + t];
    }
    for (int i = tid; i < 129; i += 256) {
      xs[i * 32 + 29] = 0.f; xs[i * 32 + 30] = 0.f; xs[i * 32 + 31] = 0.f;
    }
    __syncthreads();
    if (tid < 192) {
      const float* xb = xs + (c * 43) * 32 + t0;
      const float* wb = ws + (fc * 43) * 32 + m0;
      for (int f = 0; f < 43; ++f) {
        float4 xv = *(const float4*)(xb + f * 32);
        float4 wv = *(const float4*)(wb + f * 32);
        float xa[4] = {xv.x, xv.y, xv.z, xv.w};
        float wa[4] = {wv.x, wv.y, wv.z, wv.w};
#pragma unroll
        for (int i = 0; i < 4; ++i)
#pragma unroll
          for (int j = 0; j < 4; ++j) acc[i][j] += wa[i] * xa[j];
      }
    }
  }
  if (tid < 192) {
    const int nt = (t0 == 28) ? 1 : 4;
    for (int i = 0; i < 4; ++i)
      for (int j = 0; j < nt; ++j)
        h1[(size_t)n * 2784 + (size_t)(c * 32 + m0 + i) * 29 + (t0 + j)] = acc[i][j];
  }
}

// ------------------------------ K2: conv1 ------------------------------
__global__ __launch_bounds__(256) void k2_conv1(const float* __restrict__ h1,
                                                const float* __restrict__ w,
                                                const float* __restrict__ bias,
                                                float* __restrict__ h2,
                                                float* __restrict__ part1) {
  __shared__ __align__(16) float ins[2 * 96 * 32];
  __shared__ __align__(16) float wls[96 * 81];
  const int tid = threadIdx.x;
  const int wg = blockIdx.x;

  for (int i = tid; i < 2 * 2784; i += 256) {
    int img = i / 2784;
    int e = i - img * 2784;
    int ci = e / 29;
    int t = e - ci * 29;
    ins[img * 3072 + ci * 32 + t] = h1[(size_t)(wg * 2 + img) * 2784 + e];
  }

  const int img = tid / 96;
  const int co = tid - img * 96;
  float acc[25];
#pragma unroll
  for (int t = 0; t < 25; ++t) acc[t] = 0.f;

  for (int cc = 0; cc < 6; ++cc) {
    __syncthreads();
    for (int i = tid; i < 7680; i += 256) {
      int cw = i / 80;
      int r = i - cw * 80;
      wls[cw * 81 + r] = w[cw * 480 + cc * 80 + r];
    }
    __syncthreads();
    if (tid < 192) {
      for (int ci = 0; ci < 16; ++ci) {
        float xv[29];
#pragma unroll
        for (int j = 0; j < 29; ++j) xv[j] = ins[img * 3072 + (cc * 16 + ci) * 32 + j];
        float wv[5];
#pragma unroll
        for (int d = 0; d < 5; ++d) wv[d] = wls[co * 81 + ci * 5 + d];
#pragma unroll
        for (int t = 0; t < 25; ++t) {
          float s = acc[t];
#pragma unroll
          for (int d = 0; d < 5; ++d) s += xv[t + d] * wv[d];
          acc[t] = s;
        }
      }
    }
  }
  if (tid < 192) {
    const int n = wg * 2 + img;
    const float bval = bias[co];
    float s1 = 0.f, s2 = 0.f;
    for (int t = 0; t < 25; ++t) {
      float v = acc[t] + bval;
      h2[(size_t)n * 2400 + co * 25 + t] = v;
      s1 += v;
      s2 += v * v;
    }
    part1[((size_t)n * 96 + co) * 2 + 0] = s1;
    part1[((size_t)n * 96 + co) * 2 + 1] = s2;
  }
}

// ------------------------------ K3/K5: BN reduce -----------------------------
__global__ __launch_bounds__(256) void k3_bn1(const float* __restrict__ part,
                                              const float* __restrict__ gg,
                                              const float* __restrict__ be,
                                              float* __restrict__ ab) {
  __shared__ double sd[256], sq[256];
  const int c = blockIdx.x;
  const int t = threadIdx.x;
  double s = 0.0, q = 0.0;
  for (int n = t; n < NIMG; n += 256) {
    s += (double)part[((size_t)n * 96 + c) * 2 + 0];
    q += (double)part[((size_t)n * 96 + c) * 2 + 1];
  }
  sd[t] = s; sq[t] = q;
  __syncthreads();
  for (int off = 128; off > 0; off >>= 1) {
    if (t < off) { sd[t] += sd[t + off]; sq[t] += sq[t + off]; }
    __syncthreads();
  }
  if (t == 0) {
    double mu = sd[0] / 80000.0;
    double var = sq[0] / 80000.0 - mu * mu;
    float A = (float)((double)gg[c] / sqrt(var + 1e-5));
    ab[c * 2 + 0] = A;
    ab[c * 2 + 1] = (float)((double)be[c] - mu * (double)A);
  }
}

__global__ __launch_bounds__(256) void k5_bn2(const float* __restrict__ part,
                                              const float* __restrict__ gg,
                                              const float* __restrict__ be,
                                              float* __restrict__ ab) {
  __shared__ double sd[256], sq[256];
  const int c = blockIdx.x;
  const int t = threadIdx.x;
  double s = 0.0, q = 0.0;
  for (int n = t; n < 800; n += 256) {
    s += (double)part[((size_t)n * 16 + c) * 2 + 0];
    q += (double)part[((size_t)n * 16 + c) * 2 + 1];
  }
  sd[t] = s; sq[t] = q;
  __syncthreads();
  for (int off = 128; off > 0; off >>= 1) {
    if (t < off) { sd[t] += sd[t + off]; sq[t] += sq[t + off]; }
    __syncthreads();
  }
  if (t == 0) {
    double mu = sd[0] / 67200.0;
    double var = sq[0] / 67200.0 - mu * mu;
    float A = (float)((double)gg[c] / sqrt(var + 1e-5));
    ab[c * 2 + 0] = A;
    ab[c * 2 + 1] = (float)((double)be[c] - mu * (double)A);
  }
}

// ------------------------------ K4: conv2 ------------------------------
__global__ __launch_bounds__(256) void k4_conv2(const float* __restrict__ h2,
                                                const float* __restrict__ w,
                                                const float* __restrict__ bias,
                                                const float* __restrict__ bn1,
                                                float* __restrict__ h3,
                                                float* __restrict__ part2) {
  __shared__ __align__(16) float ins[4 * 96 * 26];
  __shared__ __align__(16) float wls[16 * 241];
  __shared__ float A1s[96], B1s[96];
  __shared__ float red[16 * 16 * 2];
  const int tid = threadIdx.x;
  const int wg = blockIdx.x;

  if (tid < 96) {
    A1s[tid] = bn1[tid * 2 + 0];
    B1s[tid] = bn1[tid * 2 + 1];
  }
  __syncthreads();
  for (int i = tid; i < 9600; i += 256) {
    int img = i / 2400;
    int e = i - img * 2400;
    int ci = e / 25;
    int t = e - ci * 25;
    float v = h2[(size_t)(wg * 4 + img) * 2400 + e];
    v = A1s[ci] * v + B1s[ci];
    v = (v >= 0.f) ? v : 0.01f * v;
    ins[img * 2496 + ci * 26 + t] = v;
  }
  for (int i = tid; i < 4 * 96; i += 256) ins[(i / 96) * 2496 + (i % 96) * 26 + 25] = 0.f;

  const int img = tid >> 6;
  const int co = (tid >> 2) & 15;
  const int tg = tid & 3;
  const int t0s[4] = {0, 6, 11, 16};
  const int t0 = t0s[tg];
  const int tl = (tg == 0) ? 6 : 5;
  float acc[6] = {0.f, 0.f, 0.f, 0.f, 0.f, 0.f};

  for (int cc = 0; cc < 2; ++cc) {
    __syncthreads();
    for (int i = tid; i < 3840; i += 256) {
      int cw = i / 240;
      int r = i - cw * 240;
      wls[cw * 241 + r] = w[cw * 480 + cc * 240 + r];
    }
    __syncthreads();
    for (int ci = 0; ci < 48; ++ci) {
      float xv[10];
#pragma unroll
      for (int j = 0; j < 10; ++j) xv[j] = ins[img * 2496 + (cc * 48 + ci) * 26 + t0 + j];
      float wv[5];
#pragma unroll
      for (int d = 0; d < 5; ++d) wv[d] = wls[co * 241 + ci * 5 + d];
#pragma unroll
      for (int t = 0; t < 6; ++t) {
        float s = acc[t];
#pragma unroll
        for (int d = 0; d < 5; ++d) s += xv[t + d] * wv[d];
        acc[t] = s;
      }
    }
  }
  const float bval = bias[co];
  float s1 = 0.f, s2 = 0.f;
  const int n = wg * 4 + img;
  for (int t = 0; t < 6; ++t) {
    if (t < tl) {
      float v = acc[t] + bval;
      h3[(size_t)n * 336 + co * 21 + t0 + t] = v;
      s1 += v;
      s2 += v * v;
    }
  }
  red[(co * 16 + img * 4 + tg) * 2 + 0] = s1;
  red[(co * 16 + img * 4 + tg) * 2 + 1] = s2;
  __syncthreads();
  if (tid < 16) {
    float s = 0.f, q = 0.f;
    for (int k = 0; k < 16; ++k) {
      s += red[(tid * 16 + k) * 2 + 0];
      q += red[(tid * 16 + k) * 2 + 1];
    }
    part2[((size_t)wg * 16 + tid) * 2 + 0] = s;
    part2[((size_t)wg * 16 + tid) * 2 + 1] = q;
  }
}

// ------------------------------ K6: OAS + Cholesky ---------------------------
__global__ __launch_bounds__(256) void k6_oas(const float* __restrict__ h3,
                                              const float* __restrict__ bn2,
                                              float* __restrict__ xd,
                                              float* __restrict__ xo) {
  __shared__ float X[4][21 * 17 + 3];
  __shared__ float A[4][16 * 17];
  __shared__ float mcol[4][16];
  const int tid = threadIdx.x;
  const int wid = tid >> 6;
  const int lane = tid & 63;
  const int n = blockIdx.x * 4 + wid;
  const float* hp = h3 + (size_t)n * 336;

  for (int e = lane; e < 336; e += 64) {
    int c = e / 21;
    int t = e - c * 21;
    float v = hp[e];
    v = bn2[c * 2 + 0] * v + bn2[c * 2 + 1];
    v = (v >= 0.f) ? v : 0.01f * v;
    X[wid][t * 17 + c] = v;
  }
  __syncthreads();
  if (lane < 16) {
    float s = 0.f;
    for (int t = 0; t < 21; ++t) s += X[wid][t * 17 + lane];
    mcol[wid][lane] = s * (1.f / 21.f);
  }
  __syncthreads();
  for (int e = lane; e < 336; e += 64) {
    int t = e / 16;
    int c = e - t * 16;
    X[wid][t * 17 + c] -= mcol[wid][c];
  }
  __syncthreads();

  float tr_p = 0.f, al_p = 0.f;
  float ent[3];
  int ei[3], ej[3], ne = 0;
  for (int e = lane; e < 136; e += 64) {
    int i = 0, e2 = e;
    while (e2 >= 16 - i) { e2 -= 16 - i; i++; }
    int j = i + e2;
    float s = 0.f;
    for (int t = 0; t < 21; ++t) s += X[wid][t * 17 + i] * X[wid][t * 17 + j];
    s *= (1.f / 20.f);
    ent[ne] = s; ei[ne] = i; ej[ne] = j; ne++;
    if (i == j) tr_p += s;
    al_p += s * s * ((i == j) ? 1.f : 2.f);
  }
  for (int m = 1; m < 64; m <<= 1) {
    tr_p += __shfl_xor(tr_p, m);
    al_p += __shfl_xor(al_p, m);
  }
  const float mu = tr_p * (1.f / 16.f);
  const float alpha = al_p * (1.f / 256.f);
  const float num = alpha + mu * mu;
  const float den = 22.f * (alpha - mu * mu * (1.f / 16.f));
  const float shr = (den == 0.f) ? 1.f : fminf(num / den, 1.f);
  for (int q = 0; q < ne; ++q) {
    float c = (1.f - shr) * ent[q] + ((ei[q] == ej[q]) ? shr * mu : 0.f);
    A[wid][ei[q] * 17 + ej[q]] = c;
    A[wid][ej[q] * 17 + ei[q]] = c;
  }
  __syncthreads();

  for (int k = 0; k < 16; ++k) {
    float akk = A[wid][k * 17 + k];
    __syncthreads();
    float d = sqrtf(akk);
    float rd = 1.f / d;
    if (lane == k) A[wid][k * 17 + k] = d;
    if (lane > k && lane < 16) A[wid][lane * 17 + k] *= rd;
    __syncthreads();
    if (lane > k && lane < 16) {
      float Lik = A[wid][lane * 17 + k];
      for (int j = k + 1; j <= lane; ++j) A[wid][lane * 17 + j] -= Lik * A[wid][j * 17 + k];
    }
    __syncthreads();
  }
  if (lane < 16) xd[(size_t)n * 16 + lane] = A[wid][lane * 17 + lane];
  for (int p = lane; p < 120; p += 64) {
    int i = 1, p2 = p;
    while (p2 >= i) { p2 -= i; i++; }
    xo[(size_t)n * 120 + p] = A[wid][i * 17 + p2];
  }
}

// ------------------------------ K0: pack W fragments ------------------------
// u32 slot within region: tile=(t*NT+nt), rem: lane=rem/4, word=rem%4.
// index = nt*16 + (lane&15), k = t*32 + 8*(lane>>4) + 2*word (+1).
// (Used as the MFMA *A* operand in k7; A and B share the lane->k map.)
__global__ __launch_bounds__(256) void k0_pack(const float* __restrict__ w0,
                                               const float* __restrict__ w1,
                                               const float* __restrict__ w2,
                                               const float* __restrict__ w3,
                                               const float* __restrict__ wxo,
                                               const float* __restrict__ who,
                                               uint32_t* __restrict__ dst) {
  int i = blockIdx.x * 256 + threadIdx.x;
  if (i >= PK2_TOT) return;
  int j = i, kind, NT;
  if (j < OFF_W1)       { kind = 0; NT = 16; }
  else if (j < OFF_W2)  { kind = 1; NT = 16; j -= OFF_W1; }
  else if (j < OFF_W3)  { kind = 2; NT = 16; j -= OFF_W2; }
  else if (j < OFF_GRZ) { kind = 3; NT = 9;  j -= OFF_W3; }
  else if (j < OFF_GNX) { kind = 4; NT = 15; j -= OFF_GRZ; }
  else if (j < OFF_GNH) { kind = 5; NT = 8;  j -= OFF_GNX; }
  else                  { kind = 6; NT = 8;  j -= OFF_GNH; }
  const int tile = j >> 8;
  const int rem = j & 255;
  const int l = rem >> 2;
  const int wd = rem & 3;
  const int t = tile / NT;
  const int nt = tile - t * NT;
  const int col = nt * 16 + (l & 15);
  const int kk = t * 32 + 8 * (l >> 4) + 2 * wd;

  float v[2];
#pragma unroll
  for (int q = 0; q < 2; ++q) {
    const int k = kk + q;
    float s = 0.f;
    if (kind == 0)      { if (k < 136) s = w0[k * 256 + col]; }
    else if (kind == 1) { s = w1[k * 256 + col]; }
    else if (kind == 2) { s = w2[k * 256 + col]; }
    else if (kind == 3) { if (col < 136) s = w3[k * 136 + col]; }
    else if (kind == 4) {
      if (k < 120) s = wxo[k * 360 + col];
      else if (k >= 128 && k < 248) s = who[(k - 128) * 360 + col];
    } else if (kind == 5) { if (k < 120 && col < 120) s = wxo[k * 360 + 240 + col]; }
    else                  { if (k < 120 && col < 120) s = who[k * 360 + 240 + col]; }
    v[q] = s;
  }
  union { f16 h[2]; uint32_t u; } cv;
  cv.h[0] = (f16)v[0];
  cv.h[1] = (f16)v[1];
  dst[i] = cv.u;
}

// ------------------------------ K7 helpers ----------------------------------
union UF { uint4 u; f16x8 h; };
union PK4 { f16 h[4]; uint2 u2; };

// swizzled LDS address: row-strided buffer, XOR byte-bits 4-6 with row&7
__device__ __forceinline__ char* swzp(void* base, int row, int b, int stride) {
  return (char*)base + row * stride + (b ^ ((row & 7) << 4));
}
// B-fragment read: [row n][k] f16 buffer (stride 512B), k-tile t, group g
__device__ __forceinline__ uint4 rdB(void* X, int t, int n, int g) {
  return *(const uint4*)swzp(X, n, 64 * t + 16 * g, 512);
}

// Streamed-A layer: A = W fragments (global, 2-stage prefetch over nt),
// B = bf[KT] (held in regs). Calls epi(nt, acc) per tile.
template <int KT, int NT, typename EPI>
__device__ __forceinline__ void layerW(const uint4* __restrict__ W,
                                       const uint4 (&bf)[KT], int l, EPI epi) {
  uint4 af[KT];
#pragma unroll
  for (int t = 0; t < KT; ++t) af[t] = W[(t * NT + 0) * 64 + l];
#pragma unroll 1
  for (int nt = 0; nt < NT; ++nt) {
    const int ntn = (nt + 1 < NT) ? nt + 1 : nt;
    uint4 afn[KT];
#pragma unroll
    for (int t = 0; t < KT; ++t) afn[t] = W[(t * NT + ntn) * 64 + l];
    f32x4 acc = {0.f, 0.f, 0.f, 0.f};
#pragma unroll
    for (int t = 0; t < KT; ++t) {
      UF a; a.u = af[t];
      UF b; b.u = bf[t];
      acc = __builtin_amdgcn_mfma_f32_16x16x32_f16(a.h, b.h, acc, 0, 0, 0);
    }
    epi(nt, acc);
#pragma unroll
    for (int t = 0; t < KT; ++t) af[t] = afn[t];
  }
}

// ------------------------------ K7: scan (1 wave / 16 rows, no barriers) ----
__global__ __launch_bounds__(64, 1) void k7_scan(
    const float* __restrict__ xdv, const float* __restrict__ xov,
    const float* __restrict__ wxd, const float* __restrict__ whd,
    const float* __restrict__ bdv, const float* __restrict__ bov,
    const uint32_t* __restrict__ pk,
    const float* __restrict__ b0, const float* __restrict__ b1,
    const float* __restrict__ b2, const float* __restrict__ b3,
    const float* __restrict__ cw, const float* __restrict__ cbv,
    float* __restrict__ out) {
  // activation buffers: [16 rows][256 k] f16, stride 512B, swizzled
  __shared__ __align__(16) f16 XA[16 * 256];
  __shared__ __align__(16) f16 XB[16 * 256];
  __shared__ __align__(16) f16 XC[16 * 256];
  __shared__ __align__(16) f16 XG[16 * 256];
  __shared__ __align__(16) float hcf[16 * 160];   // stride 640B, swizzled
  __shared__ __align__(16) float GO[16 * 512];    // stride 2048B, swizzled
  __shared__ __align__(16) float G2[16 * 96];
  __shared__ __align__(16) float xdlv[16 * 16];
  __shared__ __align__(16) float ehl[16 * 16];
  __shared__ __align__(16) float wdaT[48 * 16], whaT[48 * 16];
  __shared__ __align__(16) float b0l[256], b1l[256], b2l[256], b3l[144];
  __shared__ __align__(16) float bovl[360], bdvl[48];

  const int l = threadIdx.x;     // 0..63
  const int n = l & 15;          // batch row within group
  const int g = l >> 4;          // 0..3
  const int blk = blockIdx.x;

  const uint4* BW0 = (const uint4*)(pk + OFF_W0);
  const uint4* BW1 = (const uint4*)(pk + OFF_W1);
  const uint4* BW2 = (const uint4*)(pk + OFF_W2);
  const uint4* BW3 = (const uint4*)(pk + OFF_W3);
  const uint4* BRZ = (const uint4*)(pk + OFF_GRZ);
  const uint4* BNX = (const uint4*)(pk + OFF_GNX);
  const uint4* BNH = (const uint4*)(pk + OFF_GNH);

  // ---- init ----
  for (int i = l; i < 768; i += 64) {
    int k = i / 48, c = i - k * 48;
    wdaT[c * 16 + k] = fabsf(wxd[i]);
    whaT[c * 16 + k] = fabsf(whd[i]);
  }
  for (int i = l; i < 256; i += 64) { b0l[i] = b0[i]; b1l[i] = b1[i]; b2l[i] = b2[i]; }
  for (int i = l; i < 144; i += 64) b3l[i] = (i < 136) ? b3[i] : 0.f;
  for (int i = l; i < 360; i += 64) bovl[i] = bov[i];
  if (l < 48) bdvl[l] = fabsf(bdv[l]);
  for (int i = l; i < 16 * 160; i += 64) hcf[i] = 0.f;
  for (int i = l; i < 16 * 256; i += 64) { XA[i] = (f16)0.f; XG[i] = (f16)0.f; }
  // single wave: LDS deps ordered by lgkmcnt; no barrier needed

  // epilogue helpers ---------------------------------------------------------
  auto epi_tanh = [&](f16* Xout, const float* bl, int nt, f32x4 acc) {
    const int m0 = nt * 16 + 4 * g;
    float4 bb = *(const float4*)&bl[m0];
    PK4 p;
#pragma unroll
    for (int i = 0; i < 4; ++i) p.h[i] = (f16)ftanh(acc[i] + (&bb.x)[i]);
    *(uint2*)swzp(Xout, n, 2 * m0, 512) = p.u2;
  };
  auto epi_l3 = [&](bool last, int nt, f32x4 acc) {
    const int m0 = nt * 16 + 4 * g;
    if (m0 >= 136) return;                       // nt==8, g>=2
    float4 bb = *(const float4*)&b3l[m0];
    float* hp = (float*)swzp(hcf, n, 4 * m0, 640);
    float4 hv = *(const float4*)hp;
    float nv[4];
#pragma unroll
    for (int i = 0; i < 4; ++i) nv[i] = (&hv.x)[i] + 0.25f * (acc[i] + (&bb.x)[i]);
    *(float4*)hp = make_float4(nv[0], nv[1], nv[2], nv[3]);
    if (!last) {
      PK4 p;
#pragma unroll
      for (int i = 0; i < 4; ++i) p.h[i] = (f16)nv[i];
      *(uint2*)swzp(XA, n, 2 * m0, 512) = p.u2;
    } else {
      if (m0 >= 16) {                            // h_o -> XG at k = m0+112
        PK4 p;
#pragma unroll
        for (int i = 0; i < 4; ++i) p.h[i] = (f16)nv[i];
        *(uint2*)swzp(XG, n, 2 * (m0 + 112), 512) = p.u2;
      } else {                                   // exp(hc_d) -> ehl (f32)
        *(float4*)&ehl[n * 16 + m0] =
            make_float4(__expf(nv[0]), __expf(nv[1]), __expf(nv[2]), __expf(nv[3]));
      }
    }
  };
  auto epi_go = [&](int dst0, int nt, f32x4 acc) {
    const int m0 = dst0 + nt * 16 + 4 * g;
    *(float4*)swzp(GO, n, 4 * m0, 2048) = make_float4(acc[0], acc[1], acc[2], acc[3]);
  };

#pragma unroll 1
  for (int s = 0; s < 50; ++s) {
    // ---- load this step's gate inputs (consumed much later) ----
    for (int i = l; i < 1920; i += 64) {
      int row = i / 120, c = i - row * 120;
      *(f16*)swzp(XG, row, 2 * c, 512) =
          (f16)xov[((size_t)(blk * 16 + row) * 50 + s) * 120 + c];
    }
    for (int i = l; i < 256; i += 64) {
      int row = i >> 4, k = i & 15;
      xdlv[i] = xdv[((size_t)(blk * 16 + row) * 50 + s) * 16 + k];
    }

    // ---- ODE: 4 Euler steps ----
#pragma unroll 1
    for (int e = 0; e < 4; ++e) {
      {
        uint4 bf[5];
#pragma unroll
        for (int t = 0; t < 5; ++t) bf[t] = rdB(XA, t, n, g);
        layerW<5, 16>(BW0, bf, l, [&](int nt, f32x4 acc) { epi_tanh(XB, b0l, nt, acc); });
      }
      {
        uint4 bf[8];
#pragma unroll
        for (int t = 0; t < 8; ++t) bf[t] = rdB(XB, t, n, g);
        layerW<8, 16>(BW1, bf, l, [&](int nt, f32x4 acc) { epi_tanh(XC, b1l, nt, acc); });
      }
      {
        uint4 bf[8];
#pragma unroll
        for (int t = 0; t < 8; ++t) bf[t] = rdB(XC, t, n, g);
        layerW<8, 16>(BW2, bf, l, [&](int nt, f32x4 acc) { epi_tanh(XB, b2l, nt, acc); });
      }
      {
        uint4 bf[8];
#pragma unroll
        for (int t = 0; t < 8; ++t) bf[t] = rdB(XB, t, n, g);
        const bool last = (e == 3);
        layerW<8, 9>(BW3, bf, l, [&](int nt, f32x4 acc) { epi_l3(last, nt, acc); });
      }
    }

    // ---- gate matmuls ----
    {
      uint4 bf[8];
#pragma unroll
      for (int t = 0; t < 8; ++t) bf[t] = rdB(XG, t, n, g);
      layerW<8, 15>(BRZ, bf, l, [&](int nt, f32x4 acc) { epi_go(0, nt, acc); });
      uint4 bx[4] = {bf[0], bf[1], bf[2], bf[3]};
      layerW<4, 8>(BNX, bx, l, [&](int nt, f32x4 acc) { epi_go(256, nt, acc); });
      uint4 bh[4] = {bf[4], bf[5], bf[6], bf[7]};
      layerW<4, 8>(BNH, bh, l, [&](int nt, f32x4 acc) { epi_go(384, nt, acc); });
    }

    // ---- d-gate dots (f32 VALU, 1536 elems) ----
    for (int i = l; i < 1536; i += 64) {
      int row = i / 96, c = i - row * 96;
      const float4* sv = (const float4*)((c < 48) ? &xdlv[row * 16] : &ehl[row * 16]);
      const float4* wv = (const float4*)((c < 48) ? &wdaT[c * 16] : &whaT[(c - 48) * 16]);
      float a = 0.f;
#pragma unroll
      for (int q = 0; q < 4; ++q) {
        float4 xq = sv[q], wq = wv[q];
        a += xq.x * wq.x + xq.y * wq.y + xq.z * wq.z + xq.w * wq.w;
      }
      G2[row * 96 + c] = a;
    }

    // ---- state update ----
    for (int i = l; i < 1920; i += 64) {
      int row = i / 120, e2 = i - row * 120;
      float rr = fsigm(*(const float*)swzp(GO, row, 4 * e2, 2048) + bovl[e2]);
      float zz = fsigm(*(const float*)swzp(GO, row, 4 * (120 + e2), 2048) + bovl[120 + e2]);
      float ig = *(const float*)swzp(GO, row, 4 * (256 + e2), 2048);
      float hg = *(const float*)swzp(GO, row, 4 * (384 + e2), 2048);
      float ng = ftanh(ig + rr * hg + bovl[240 + e2]);
      float* hp = (float*)swzp(hcf, row, 4 * (16 + e2), 640);
      float ho = *hp;
      float v = ng + zz * (ho - ng);
      *hp = v;
      *(f16*)swzp(XA, row, 2 * (16 + e2), 512) = (f16)v;
    }
    for (int i = l; i < 256; i += 64) {
      int row = i >> 4, t = i & 15;
      float ixr = G2[row * 96 + t], ixi = G2[row * 96 + 16 + t], ixn = G2[row * 96 + 32 + t];
      float hhr = G2[row * 96 + 48 + t], hhi = G2[row * 96 + 64 + t], hhn = G2[row * 96 + 80 + t];
      float br = bdvl[t], bi = bdvl[16 + t], bn = bdvl[32 + t];
      float rr = fsigm(br * ixr * hhr);
      float zz = fsigm(bi * ixi * hhi);
      float sp = bn * ixn * rr * hhn;
      float ng = (sp > 20.f) ? sp : __logf(1.f + __expf(sp));
      float* hp = (float*)swzp(hcf, row, 4 * t, 640);
      float v = zz * (*hp) + (1.f - zz) * __logf(ng);
      *hp = v;
      *(f16*)swzp(XA, row, 2 * t, 512) = (f16)v;
    }
  }

  // ---- classifier ----
  for (int i = l; i < 80; i += 64) {
    int row = i / 5, c = i - row * 5;
    float a = cbv[c];
    for (int k = 0; k < 136; ++k)
      a += *(const float*)swzp(hcf, row, 4 * k, 640) * cw[k * 5 + c];
    out[(size_t)(blk * 16 + row) * 5 + c] = a;
  }
}

// ------------------------------ launch ------------------------------
extern "C" void kernel_launch(void* const* d_in, const int* in_sizes, int n_in,
                              void* d_out, int out_size, void* d_ws, size_t ws_size,
                              hipStream_t stream) {
  const float* x       = (const float*)d_in[0];
  const float* fw      = (const float*)d_in[1];
  const float* s_tri   = (const float*)d_in[2];
  const float* conv1_w = (const float*)d_in[3];
  const float* conv1_b = (const float*)d_in[4];
  const float* bn1_g   = (const float*)d_in[5];
  const float* bn1_b   = (const float*)d_in[6];
  const float* conv2_w = (const float*)d_in[7];
  const float* conv2_b = (const float*)d_in[8];
  const float* bn2_g   = (const float*)d_in[9];
  const float* bn2_b   = (const float*)d_in[10];
  const float* wx_d    = (const float*)d_in[11];
  const float* wh_d    = (const float*)d_in[12];
  const float* bias_d  = (const float*)d_in[13];
  const float* wx_o    = (const float*)d_in[14];
  const float* wh_o    = (const float*)d_in[15];
  const float* bias_o  = (const float*)d_in[16];
  const float* ode_w0  = (const float*)d_in[17];
  const float* ode_b0  = (const float*)d_in[18];
  const float* ode_w1  = (const float*)d_in[19];
  const float* ode_b1  = (const float*)d_in[20];
  const float* ode_w2  = (const float*)d_in[21];
  const float* ode_b2  = (const float*)d_in[22];
  const float* ode_w3  = (const float*)d_in[23];
  const float* ode_b3  = (const float*)d_in[24];
  const float* cls_w   = (const float*)d_in[25];
  const float* cls_b   = (const float*)d_in[26];

  float* ws = (float*)d_ws;
  float* h1  = ws;                    // 8,908,800 floats (K1->K2), then dead
  float* h3  = ws;                    // 1,075,200 floats (K4->K6)
  float* xd  = ws + 1075200;          // 51,200
  float* xo  = ws + 1126400;          // 384,000
  float* h2  = ws + 8908800;          // 7,680,000 (K2->K4), then reused by K0
  float* p1  = ws + 16588800;         // 614,400
  float* bn1 = ws + 17203200;         // 192
  float* p2  = ws + 17203392;         // 25,600
  float* bn2 = ws + 17228992;         // 32
  uint32_t* pk = (uint32_t*)(ws + 8908800);  // packed W-fragments (dead h2)

  hipLaunchKernelGGL(k1_fb,   dim3(NIMG),   dim3(256), 0, stream, x, fw, s_tri, h1);
  hipLaunchKernelGGL(k2_conv1,dim3(NIMG/2), dim3(256), 0, stream, h1, conv1_w, conv1_b, h2, p1);
  hipLaunchKernelGGL(k3_bn1,  dim3(96),     dim3(256), 0, stream, p1, bn1_g, bn1_b, bn1);
  hipLaunchKernelGGL(k4_conv2,dim3(NIMG/4), dim3(256), 0, stream, h2, conv2_w, conv2_b, bn1, h3, p2);
  hipLaunchKernelGGL(k5_bn2,  dim3(16),     dim3(256), 0, stream, p2, bn2_g, bn2_b, bn2);
  hipLaunchKernelGGL(k6_oas,  dim3(NIMG/4), dim3(256), 0, stream, h3, bn2, xd, xo);
  hipLaunchKernelGGL(k0_pack, dim3((PK2_TOT + 255) / 256), dim3(256), 0, stream,
                     ode_w0, ode_w1, ode_w2, ode_w3, wx_o, wh_o, pk);
  hipLaunchKernelGGL(k7_scan, dim3(4),      dim3(64), 0, stream,
                     xd, xo, wx_d, wh_d, bias_d, bias_o, pk,
                     ode_b0, ode_b1, ode_b2, ode_b3, cls_w, cls_b, (float*)d_out);
}

// Round 11
// 2261.009 us; speedup vs baseline: 2.4015x; 2.4015x over previous
//
#include <hip/hip_runtime.h>
#include <math.h>

// ---------------------------------------------------------------------------
// ODERGRU pipeline for MI355X.
//  K1: einsum -> h1 (3200,96,29)
//  K2: conv1d 96->96 k5 + bias -> h2 + BN partials
//  K3: BN1 reduce   K5: BN2 reduce  (f64 tree)
//  K4: conv1d 96->16 k5 (BN1+lrelu on load) -> h3 + BN2 partials
//  K6: OAS + Cholesky -> x_d, x_o
//  K0: pack ODE/GRU weights f32 -> f16 fragments (MFMA lane order)
//  K7: 4 blocks x 4 waves x 16 rows. Swapped MFMA (A=W streamed depth-2
//      prefetch, B=X^T from LDS read once/layer/wave). Wave w owns N-tiles
//      {w, w+4, ...}. 18 barriers/step. b64 packed activation writes.
// ---------------------------------------------------------------------------

#define BB 64
#define NIMG 3200

typedef _Float16 f16;
typedef _Float16 f16x8 __attribute__((ext_vector_type(8)));
typedef float f32x4 __attribute__((ext_vector_type(4)));

__device__ __forceinline__ float fsigm(float x) {
  return __fdividef(1.f, 1.f + __expf(-x));
}
__device__ __forceinline__ float ftanh(float x) {
  return 1.f - __fdividef(2.f, __expf(2.f * x) + 1.f);
}

// pk region offsets (u32 units)
#define OFF_W0  0
#define OFF_W1  20480
#define OFF_W2  53248
#define OFF_W3  86016
#define OFF_GRZ 104448
#define OFF_GNX 135168
#define OFF_GNH 143360
#define PK2_TOT 151552

// ------------------------------ K1: filterbank ------------------------------
__global__ __launch_bounds__(256) void k1_fb(const float* __restrict__ x,
                                             const float* __restrict__ fw,
                                             const float* __restrict__ st,
                                             float* __restrict__ h1) {
  __shared__ __align__(16) float ws[129 * 32];
  __shared__ __align__(16) float xs[129 * 32];
  const int tid = threadIdx.x;
  const int n = blockIdx.x;
  const float* xp = x + (size_t)n * 11223;

  for (int i = tid; i < 4128; i += 256) ws[i] = fw[i] * st[i];

  float acc[4][4];
#pragma unroll
  for (int i = 0; i < 4; ++i)
#pragma unroll
    for (int j = 0; j < 4; ++j) acc[i][j] = 0.f;

  const int c = tid / 64;
  const int rem = tid % 64;
  const int m0 = (rem / 8) * 4;
  const int t0 = (rem % 8) * 4;

  for (int fc = 0; fc < 3; ++fc) {
    __syncthreads();
    for (int i = tid; i < 3741; i += 256) {
      int cc = i / 1247;
      int r = i - cc * 1247;
      int f = r / 29;
      int t = r - f * 29;
      xs[(cc * 43 + f) * 32 + t] = xp[cc * 3741 + (fc * 43 + f) * 29 + t];
    }
    for (int i = tid; i < 129; i += 256) {
      xs[i * 32 + 29] = 0.f; xs[i * 32 + 30] = 0.f; xs[i * 32 + 31] = 0.f;
    }
    __syncthreads();
    if (tid < 192) {
      const float* xb = xs + (c * 43) * 32 + t0;
      const float* wb = ws + (fc * 43) * 32 + m0;
      for (int f = 0; f < 43; ++f) {
        float4 xv = *(const float4*)(xb + f * 32);
        float4 wv = *(const float4*)(wb + f * 32);
        float xa[4] = {xv.x, xv.y, xv.z, xv.w};
        float wa[4] = {wv.x, wv.y, wv.z, wv.w};
#pragma unroll
        for (int i = 0; i < 4; ++i)
#pragma unroll
          for (int j = 0; j < 4; ++j) acc[i][j] += wa[i] * xa[j];
      }
    }
  }
  if (tid < 192) {
    const int nt = (t0 == 28) ? 1 : 4;
    for (int i = 0; i < 4; ++i)
      for (int j = 0; j < nt; ++j)
        h1[(size_t)n * 2784 + (size_t)(c * 32 + m0 + i) * 29 + (t0 + j)] = acc[i][j];
  }
}

// ------------------------------ K2: conv1 ------------------------------
__global__ __launch_bounds__(256) void k2_conv1(const float* __restrict__ h1,
                                                const float* __restrict__ w,
                                                const float* __restrict__ bias,
                                                float* __restrict__ h2,
                                                float* __restrict__ part1) {
  __shared__ __align__(16) float ins[2 * 96 * 32];
  __shared__ __align__(16) float wls[96 * 81];
  const int tid = threadIdx.x;
  const int wg = blockIdx.x;

  for (int i = tid; i < 2 * 2784; i += 256) {
    int img = i / 2784;
    int e = i - img * 2784;
    int ci = e / 29;
    int t = e - ci * 29;
    ins[img * 3072 + ci * 32 + t] = h1[(size_t)(wg * 2 + img) * 2784 + e];
  }

  const int img = tid / 96;
  const int co = tid - img * 96;
  float acc[25];
#pragma unroll
  for (int t = 0; t < 25; ++t) acc[t] = 0.f;

  for (int cc = 0; cc < 6; ++cc) {
    __syncthreads();
    for (int i = tid; i < 7680; i += 256) {
      int cw = i / 80;
      int r = i - cw * 80;
      wls[cw * 81 + r] = w[cw * 480 + cc * 80 + r];
    }
    __syncthreads();
    if (tid < 192) {
      for (int ci = 0; ci < 16; ++ci) {
        float xv[29];
#pragma unroll
        for (int j = 0; j < 29; ++j) xv[j] = ins[img * 3072 + (cc * 16 + ci) * 32 + j];
        float wv[5];
#pragma unroll
        for (int d = 0; d < 5; ++d) wv[d] = wls[co * 81 + ci * 5 + d];
#pragma unroll
        for (int t = 0; t < 25; ++t) {
          float s = acc[t];
#pragma unroll
          for (int d = 0; d < 5; ++d) s += xv[t + d] * wv[d];
          acc[t] = s;
        }
      }
    }
  }
  if (tid < 192) {
    const int n = wg * 2 + img;
    const float bval = bias[co];
    float s1 = 0.f, s2 = 0.f;
    for (int t = 0; t < 25; ++t) {
      float v = acc[t] + bval;
      h2[(size_t)n * 2400 + co * 25 + t] = v;
      s1 += v;
      s2 += v * v;
    }
    part1[((size_t)n * 96 + co) * 2 + 0] = s1;
    part1[((size_t)n * 96 + co) * 2 + 1] = s2;
  }
}

// ------------------------------ K3/K5: BN reduce -----------------------------
__global__ __launch_bounds__(256) void k3_bn1(const float* __restrict__ part,
                                              const float* __restrict__ gg,
                                              const float* __restrict__ be,
                                              float* __restrict__ ab) {
  __shared__ double sd[256], sq[256];
  const int c = blockIdx.x;
  const int t = threadIdx.x;
  double s = 0.0, q = 0.0;
  for (int n = t; n < NIMG; n += 256) {
    s += (double)part[((size_t)n * 96 + c) * 2 + 0];
    q += (double)part[((size_t)n * 96 + c) * 2 + 1];
  }
  sd[t] = s; sq[t] = q;
  __syncthreads();
  for (int off = 128; off > 0; off >>= 1) {
    if (t < off) { sd[t] += sd[t + off]; sq[t] += sq[t + off]; }
    __syncthreads();
  }
  if (t == 0) {
    double mu = sd[0] / 80000.0;
    double var = sq[0] / 80000.0 - mu * mu;
    float A = (float)((double)gg[c] / sqrt(var + 1e-5));
    ab[c * 2 + 0] = A;
    ab[c * 2 + 1] = (float)((double)be[c] - mu * (double)A);
  }
}

__global__ __launch_bounds__(256) void k5_bn2(const float* __restrict__ part,
                                              const float* __restrict__ gg,
                                              const float* __restrict__ be,
                                              float* __restrict__ ab) {
  __shared__ double sd[256], sq[256];
  const int c = blockIdx.x;
  const int t = threadIdx.x;
  double s = 0.0, q = 0.0;
  for (int n = t; n < 800; n += 256) {
    s += (double)part[((size_t)n * 16 + c) * 2 + 0];
    q += (double)part[((size_t)n * 16 + c) * 2 + 1];
  }
  sd[t] = s; sq[t] = q;
  __syncthreads();
  for (int off = 128; off > 0; off >>= 1) {
    if (t < off) { sd[t] += sd[t + off]; sq[t] += sq[t + off]; }
    __syncthreads();
  }
  if (t == 0) {
    double mu = sd[0] / 67200.0;
    double var = sq[0] / 67200.0 - mu * mu;
    float A = (float)((double)gg[c] / sqrt(var + 1e-5));
    ab[c * 2 + 0] = A;
    ab[c * 2 + 1] = (float)((double)be[c] - mu * (double)A);
  }
}

// ------------------------------ K4: conv2 ------------------------------
__global__ __launch_bounds__(256) void k4_conv2(const float* __restrict__ h2,
                                                const float* __restrict__ w,
                                                const float* __restrict__ bias,
                                                const float* __restrict__ bn1,
                                                float* __restrict__ h3,
                                                float* __restrict__ part2) {
  __shared__ __align__(16) float ins[4 * 96 * 26];
  __shared__ __align__(16) float wls[16 * 241];
  __shared__ float A1s[96], B1s[96];
  __shared__ float red[16 * 16 * 2];
  const int tid = threadIdx.x;
  const int wg = blockIdx.x;

  if (tid < 96) {
    A1s[tid] = bn1[tid * 2 + 0];
    B1s[tid] = bn1[tid * 2 + 1];
  }
  __syncthreads();
  for (int i = tid; i < 9600; i += 256) {
    int img = i / 2400;
    int e = i - img * 2400;
    int ci = e / 25;
    int t = e - ci * 25;
    float v = h2[(size_t)(wg * 4 + img) * 2400 + e];
    v = A1s[ci] * v + B1s[ci];
    v = (v >= 0.f) ? v : 0.01f * v;
    ins[img * 2496 + ci * 26 + t] = v;
  }
  for (int i = tid; i < 4 * 96; i += 256) ins[(i / 96) * 2496 + (i % 96) * 26 + 25] = 0.f;

  const int img = tid >> 6;
  const int co = (tid >> 2) & 15;
  const int tg = tid & 3;
  const int t0s[4] = {0, 6, 11, 16};
  const int t0 = t0s[tg];
  const int tl = (tg == 0) ? 6 : 5;
  float acc[6] = {0.f, 0.f, 0.f, 0.f, 0.f, 0.f};

  for (int cc = 0; cc < 2; ++cc) {
    __syncthreads();
    for (int i = tid; i < 3840; i += 256) {
      int cw = i / 240;
      int r = i - cw * 240;
      wls[cw * 241 + r] = w[cw * 480 + cc * 240 + r];
    }
    __syncthreads();
    for (int ci = 0; ci < 48; ++ci) {
      float xv[10];
#pragma unroll
      for (int j = 0; j < 10; ++j) xv[j] = ins[img * 2496 + (cc * 48 + ci) * 26 + t0 + j];
      float wv[5];
#pragma unroll
      for (int d = 0; d < 5; ++d) wv[d] = wls[co * 241 + ci * 5 + d];
#pragma unroll
      for (int t = 0; t < 6; ++t) {
        float s = acc[t];
#pragma unroll
        for (int d = 0; d < 5; ++d) s += xv[t + d] * wv[d];
        acc[t] = s;
      }
    }
  }
  const float bval = bias[co];
  float s1 = 0.f, s2 = 0.f;
  const int n = wg * 4 + img;
  for (int t = 0; t < 6; ++t) {
    if (t < tl) {
      float v = acc[t] + bval;
      h3[(size_t)n * 336 + co * 21 + t0 + t] = v;
      s1 += v;
      s2 += v * v;
    }
  }
  red[(co * 16 + img * 4 + tg) * 2 + 0] = s1;
  red[(co * 16 + img * 4 + tg) * 2 + 1] = s2;
  __syncthreads();
  if (tid < 16) {
    float s = 0.f, q = 0.f;
    for (int k = 0; k < 16; ++k) {
      s += red[(tid * 16 + k) * 2 + 0];
      q += red[(tid * 16 + k) * 2 + 1];
    }
    part2[((size_t)wg * 16 + tid) * 2 + 0] = s;
    part2[((size_t)wg * 16 + tid) * 2 + 1] = q;
  }
}

// ------------------------------ K6: OAS + Cholesky ---------------------------
__global__ __launch_bounds__(256) void k6_oas(const float* __restrict__ h3,
                                              const float* __restrict__ bn2,
                                              float* __restrict__ xd,
                                              float* __restrict__ xo) {
  __shared__ float X[4][21 * 17 + 3];
  __shared__ float A[4][16 * 17];
  __shared__ float mcol[4][16];
  const int tid = threadIdx.x;
  const int wid = tid >> 6;
  const int lane = tid & 63;
  const int n = blockIdx.x * 4 + wid;
  const float* hp = h3 + (size_t)n * 336;

  for (int e = lane; e < 336; e += 64) {
    int c = e / 21;
    int t = e - c * 21;
    float v = hp[e];
    v = bn2[c * 2 + 0] * v + bn2[c * 2 + 1];
    v = (v >= 0.f) ? v : 0.01f * v;
    X[wid][t * 17 + c] = v;
  }
  __syncthreads();
  if (lane < 16) {
    float s = 0.f;
    for (int t = 0; t < 21; ++t) s += X[wid][t * 17 + lane];
    mcol[wid][lane] = s * (1.f / 21.f);
  }
  __syncthreads();
  for (int e = lane; e < 336; e += 64) {
    int t = e / 16;
    int c = e - t * 16;
    X[wid][t * 17 + c] -= mcol[wid][c];
  }
  __syncthreads();

  float tr_p = 0.f, al_p = 0.f;
  float ent[3];
  int ei[3], ej[3], ne = 0;
  for (int e = lane; e < 136; e += 64) {
    int i = 0, e2 = e;
    while (e2 >= 16 - i) { e2 -= 16 - i; i++; }
    int j = i + e2;
    float s = 0.f;
    for (int t = 0; t < 21; ++t) s += X[wid][t * 17 + i] * X[wid][t * 17 + j];
    s *= (1.f / 20.f);
    ent[ne] = s; ei[ne] = i; ej[ne] = j; ne++;
    if (i == j) tr_p += s;
    al_p += s * s * ((i == j) ? 1.f : 2.f);
  }
  for (int m = 1; m < 64; m <<= 1) {
    tr_p += __shfl_xor(tr_p, m);
    al_p += __shfl_xor(al_p, m);
  }
  const float mu = tr_p * (1.f / 16.f);
  const float alpha = al_p * (1.f / 256.f);
  const float num = alpha + mu * mu;
  const float den = 22.f * (alpha - mu * mu * (1.f / 16.f));
  const float shr = (den == 0.f) ? 1.f : fminf(num / den, 1.f);
  for (int q = 0; q < ne; ++q) {
    float c = (1.f - shr) * ent[q] + ((ei[q] == ej[q]) ? shr * mu : 0.f);
    A[wid][ei[q] * 17 + ej[q]] = c;
    A[wid][ej[q] * 17 + ei[q]] = c;
  }
  __syncthreads();

  for (int k = 0; k < 16; ++k) {
    float akk = A[wid][k * 17 + k];
    __syncthreads();
    float d = sqrtf(akk);
    float rd = 1.f / d;
    if (lane == k) A[wid][k * 17 + k] = d;
    if (lane > k && lane < 16) A[wid][lane * 17 + k] *= rd;
    __syncthreads();
    if (lane > k && lane < 16) {
      float Lik = A[wid][lane * 17 + k];
      for (int j = k + 1; j <= lane; ++j) A[wid][lane * 17 + j] -= Lik * A[wid][j * 17 + k];
    }
    __syncthreads();
  }
  if (lane < 16) xd[(size_t)n * 16 + lane] = A[wid][lane * 17 + lane];
  for (int p = lane; p < 120; p += 64) {
    int i = 1, p2 = p;
    while (p2 >= i) { p2 -= i; i++; }
    xo[(size_t)n * 120 + p] = A[wid][i * 17 + p2];
  }
}

// ------------------------------ K0: pack W fragments ------------------------
// u32 slot within region: tile=(t*NT+nt), rem: lane=rem/4, word=rem%4.
// index = nt*16 + (lane&15), k = t*32 + 8*(lane>>4) + 2*word (+1).
// (Used as the MFMA *A* operand in k7; A and B share the lane->k map.)
__global__ __launch_bounds__(256) void k0_pack(const float* __restrict__ w0,
                                               const float* __restrict__ w1,
                                               const float* __restrict__ w2,
                                               const float* __restrict__ w3,
                                               const float* __restrict__ wxo,
                                               const float* __restrict__ who,
                                               uint32_t* __restrict__ dst) {
  int i = blockIdx.x * 256 + threadIdx.x;
  if (i >= PK2_TOT) return;
  int j = i, kind, NT;
  if (j < OFF_W1)       { kind = 0; NT = 16; }
  else if (j < OFF_W2)  { kind = 1; NT = 16; j -= OFF_W1; }
  else if (j < OFF_W3)  { kind = 2; NT = 16; j -= OFF_W2; }
  else if (j < OFF_GRZ) { kind = 3; NT = 9;  j -= OFF_W3; }
  else if (j < OFF_GNX) { kind = 4; NT = 15; j -= OFF_GRZ; }
  else if (j < OFF_GNH) { kind = 5; NT = 8;  j -= OFF_GNX; }
  else                  { kind = 6; NT = 8;  j -= OFF_GNH; }
  const int tile = j >> 8;
  const int rem = j & 255;
  const int l = rem >> 2;
  const int wd = rem & 3;
  const int t = tile / NT;
  const int nt = tile - t * NT;
  const int col = nt * 16 + (l & 15);
  const int kk = t * 32 + 8 * (l >> 4) + 2 * wd;

  float v[2];
#pragma unroll
  for (int q = 0; q < 2; ++q) {
    const int k = kk + q;
    float s = 0.f;
    if (kind == 0)      { if (k < 136) s = w0[k * 256 + col]; }
    else if (kind == 1) { s = w1[k * 256 + col]; }
    else if (kind == 2) { s = w2[k * 256 + col]; }
    else if (kind == 3) { if (col < 136) s = w3[k * 136 + col]; }
    else if (kind == 4) {
      if (k < 120) s = wxo[k * 360 + col];
      else if (k >= 128 && k < 248) s = who[(k - 128) * 360 + col];
    } else if (kind == 5) { if (k < 120 && col < 120) s = wxo[k * 360 + 240 + col]; }
    else                  { if (k < 120 && col < 120) s = who[k * 360 + 240 + col]; }
    v[q] = s;
  }
  union { f16 h[2]; uint32_t u; } cv;
  cv.h[0] = (f16)v[0];
  cv.h[1] = (f16)v[1];
  dst[i] = cv.u;
}

// ------------------------------ K7 helpers ----------------------------------
union UF { uint4 u; f16x8 h; };
union PK4 { f16 h[4]; uint2 u2; };

// swizzled LDS address: row-strided buffer, XOR byte-bits 4-6 with row&7
__device__ __forceinline__ char* swzp(void* base, int row, int b, int stride) {
  return (char*)base + row * stride + (b ^ ((row & 7) << 4));
}
// B-fragment read: [row n][k] f16 buffer (stride 512B), k-tile t, group g
__device__ __forceinline__ uint4 rdB(void* X, int t, int n, int g) {
  return *(const uint4*)swzp(X, n, 64 * t + 16 * g, 512);
}

// Streamed-A layer, wave w owns tiles {w, w+4, ...} < NT, depth-2 prefetch.
template <int KT, int NT, typename EPI>
__device__ __forceinline__ void layerW(const uint4* __restrict__ W,
                                       const uint4 (&bf)[KT], int w, int l,
                                       EPI epi) {
  const int cnt = (NT - w + 3) >> 2;
  uint4 a0[KT], a1[KT];
#pragma unroll
  for (int t = 0; t < KT; ++t) a0[t] = W[(t * NT + w) * 64 + l];
  if (cnt > 1) {
#pragma unroll
    for (int t = 0; t < KT; ++t) a1[t] = W[(t * NT + w + 4) * 64 + l];
  }
#pragma unroll 1
  for (int i = 0; i < cnt; ++i) {
    const int nt = w + 4 * i;
    f32x4 acc = {0.f, 0.f, 0.f, 0.f};
#pragma unroll
    for (int t = 0; t < KT; ++t) {
      UF a; a.u = a0[t];
      UF b; b.u = bf[t];
      acc = __builtin_amdgcn_mfma_f32_16x16x32_f16(a.h, b.h, acc, 0, 0, 0);
    }
#pragma unroll
    for (int t = 0; t < KT; ++t) a0[t] = a1[t];
    if (i + 2 < cnt) {
      const int ntn = w + 4 * (i + 2);
#pragma unroll
      for (int t = 0; t < KT; ++t) a1[t] = W[(t * NT + ntn) * 64 + l];
    }
    epi(nt, acc);
  }
}

// ------------------------------ K7: scan (4 waves, swapped MFMA) ------------
__global__ __launch_bounds__(256, 1) void k7_scan(
    const float* __restrict__ xdv, const float* __restrict__ xov,
    const float* __restrict__ wxd, const float* __restrict__ whd,
    const float* __restrict__ bdv, const float* __restrict__ bov,
    const uint32_t* __restrict__ pk,
    const float* __restrict__ b0, const float* __restrict__ b1,
    const float* __restrict__ b2, const float* __restrict__ b3,
    const float* __restrict__ cw, const float* __restrict__ cbv,
    float* __restrict__ out) {
  // activation buffers: [16 rows][256 k] f16, stride 512B, swizzled
  __shared__ __align__(16) f16 XA[16 * 256];
  __shared__ __align__(16) f16 XB[16 * 256];
  __shared__ __align__(16) f16 XC[16 * 256];
  __shared__ __align__(16) f16 XG[16 * 256];
  __shared__ __align__(16) float hcf[16 * 160];   // stride 640B, swizzled
  __shared__ __align__(16) float GO[16 * 512];    // stride 2048B, swizzled
  __shared__ __align__(16) float G2[16 * 96];
  __shared__ __align__(16) float xdlv[16 * 16];
  __shared__ __align__(16) float ehl[16 * 16];
  __shared__ __align__(16) float wdaT[48 * 16], whaT[48 * 16];
  __shared__ __align__(16) float b0l[256], b1l[256], b2l[256], b3l[144];
  __shared__ __align__(16) float bovl[360], bdvl[48];

  const int tid = threadIdx.x;   // 0..255
  const int w = tid >> 6;        // wave 0..3
  const int l = tid & 63;
  const int n = l & 15;          // batch row within group
  const int g = l >> 4;          // 0..3
  const int blk = blockIdx.x;

  const uint4* BW0 = (const uint4*)(pk + OFF_W0);
  const uint4* BW1 = (const uint4*)(pk + OFF_W1);
  const uint4* BW2 = (const uint4*)(pk + OFF_W2);
  const uint4* BW3 = (const uint4*)(pk + OFF_W3);
  const uint4* BRZ = (const uint4*)(pk + OFF_GRZ);
  const uint4* BNX = (const uint4*)(pk + OFF_GNX);
  const uint4* BNH = (const uint4*)(pk + OFF_GNH);

  // ---- init ----
  for (int i = tid; i < 768; i += 256) {
    int k = i / 48, c = i - k * 48;
    wdaT[c * 16 + k] = fabsf(wxd[i]);
    whaT[c * 16 + k] = fabsf(whd[i]);
  }
  for (int i = tid; i < 256; i += 256) { b0l[i] = b0[i]; b1l[i] = b1[i]; b2l[i] = b2[i]; }
  if (tid < 144) b3l[tid] = (tid < 136) ? b3[tid] : 0.f;
  for (int i = tid; i < 360; i += 256) bovl[i] = bov[i];
  if (tid < 48) bdvl[tid] = fabsf(bdv[tid]);
  for (int i = tid; i < 16 * 160; i += 256) hcf[i] = 0.f;
  for (int i = tid; i < 16 * 256; i += 256) { XA[i] = (f16)0.f; XG[i] = (f16)0.f; }
  __syncthreads();

  // epilogue helpers ---------------------------------------------------------
  auto epi_tanh = [&](f16* Xout, const float* bl, int nt, f32x4 acc) {
    const int m0 = nt * 16 + 4 * g;
    float4 bb = *(const float4*)&bl[m0];
    PK4 p;
#pragma unroll
    for (int i = 0; i < 4; ++i) p.h[i] = (f16)ftanh(acc[i] + (&bb.x)[i]);
    *(uint2*)swzp(Xout, n, 2 * m0, 512) = p.u2;
  };
  auto epi_l3 = [&](bool last, int nt, f32x4 acc) {
    const int m0 = nt * 16 + 4 * g;
    if (m0 >= 136) return;                       // nt==8, g>=2
    float4 bb = *(const float4*)&b3l[m0];
    float* hp = (float*)swzp(hcf, n, 4 * m0, 640);
    float4 hv = *(const float4*)hp;
    float nv[4];
#pragma unroll
    for (int i = 0; i < 4; ++i) nv[i] = (&hv.x)[i] + 0.25f * (acc[i] + (&bb.x)[i]);
    *(float4*)hp = make_float4(nv[0], nv[1], nv[2], nv[3]);
    if (!last) {
      PK4 p;
#pragma unroll
      for (int i = 0; i < 4; ++i) p.h[i] = (f16)nv[i];
      *(uint2*)swzp(XA, n, 2 * m0, 512) = p.u2;
    } else {
      if (m0 >= 16) {                            // h_o -> XG at k = m0+112
        PK4 p;
#pragma unroll
        for (int i = 0; i < 4; ++i) p.h[i] = (f16)nv[i];
        *(uint2*)swzp(XG, n, 2 * (m0 + 112), 512) = p.u2;
      } else {                                   // exp(hc_d) -> ehl (f32)
        *(float4*)&ehl[n * 16 + m0] =
            make_float4(__expf(nv[0]), __expf(nv[1]), __expf(nv[2]), __expf(nv[3]));
      }
    }
  };
  auto epi_go = [&](int dst0, int nt, f32x4 acc) {
    const int m0 = dst0 + nt * 16 + 4 * g;
    *(float4*)swzp(GO, n, 4 * m0, 2048) = make_float4(acc[0], acc[1], acc[2], acc[3]);
  };

#pragma unroll 1
  for (int s = 0; s < 50; ++s) {
    // ---- stage this step's gate inputs (consumed after several barriers) ----
    for (int i = tid; i < 1920; i += 256) {
      int row = i / 120, c = i - row * 120;
      *(f16*)swzp(XG, row, 2 * c, 512) =
          (f16)xov[((size_t)(blk * 16 + row) * 50 + s) * 120 + c];
    }
    if (tid < 256) {
      int row = tid >> 4, k = tid & 15;
      xdlv[tid] = xdv[((size_t)(blk * 16 + row) * 50 + s) * 16 + k];
    }

    // ---- ODE: 4 Euler steps; 4 phases each ----
#pragma unroll 1
    for (int e = 0; e < 4; ++e) {
      {
        uint4 bf[5];
#pragma unroll
        for (int t = 0; t < 5; ++t) bf[t] = rdB(XA, t, n, g);
        layerW<5, 16>(BW0, bf, w, l, [&](int nt, f32x4 acc) { epi_tanh(XB, b0l, nt, acc); });
      }
      __syncthreads();
      {
        uint4 bf[8];
#pragma unroll
        for (int t = 0; t < 8; ++t) bf[t] = rdB(XB, t, n, g);
        layerW<8, 16>(BW1, bf, w, l, [&](int nt, f32x4 acc) { epi_tanh(XC, b1l, nt, acc); });
      }
      __syncthreads();
      {
        uint4 bf[8];
#pragma unroll
        for (int t = 0; t < 8; ++t) bf[t] = rdB(XC, t, n, g);
        layerW<8, 16>(BW2, bf, w, l, [&](int nt, f32x4 acc) { epi_tanh(XB, b2l, nt, acc); });
      }
      __syncthreads();
      {
        uint4 bf[8];
#pragma unroll
        for (int t = 0; t < 8; ++t) bf[t] = rdB(XB, t, n, g);
        const bool last = (e == 3);
        layerW<8, 9>(BW3, bf, w, l, [&](int nt, f32x4 acc) { epi_l3(last, nt, acc); });
      }
      __syncthreads();
    }

    // ---- gate matmuls + d-gate dots, one phase ----
    {
      uint4 bf[8];
#pragma unroll
      for (int t = 0; t < 8; ++t) bf[t] = rdB(XG, t, n, g);
      layerW<8, 15>(BRZ, bf, w, l, [&](int nt, f32x4 acc) { epi_go(0, nt, acc); });
      uint4 bx[4] = {bf[0], bf[1], bf[2], bf[3]};
      layerW<4, 8>(BNX, bx, w, l, [&](int nt, f32x4 acc) { epi_go(256, nt, acc); });
      uint4 bh[4] = {bf[4], bf[5], bf[6], bf[7]};
      layerW<4, 8>(BNH, bh, w, l, [&](int nt, f32x4 acc) { epi_go(384, nt, acc); });
    }
    for (int i = tid; i < 1536; i += 256) {
      int row = i / 96, c = i - row * 96;
      const float4* sv = (const float4*)((c < 48) ? &xdlv[row * 16] : &ehl[row * 16]);
      const float4* wv = (const float4*)((c < 48) ? &wdaT[c * 16] : &whaT[(c - 48) * 16]);
      float a = 0.f;
#pragma unroll
      for (int q = 0; q < 4; ++q) {
        float4 xq = sv[q], wq = wv[q];
        a += xq.x * wq.x + xq.y * wq.y + xq.z * wq.z + xq.w * wq.w;
      }
      G2[row * 96 + c] = a;
    }
    __syncthreads();

    // ---- state update (writes hcf AND next-step XA) ----
    for (int i = tid; i < 1920; i += 256) {
      int row = i / 120, e2 = i - row * 120;
      float rr = fsigm(*(const float*)swzp(GO, row, 4 * e2, 2048) + bovl[e2]);
      float zz = fsigm(*(const float*)swzp(GO, row, 4 * (120 + e2), 2048) + bovl[120 + e2]);
      float ig = *(const float*)swzp(GO, row, 4 * (256 + e2), 2048);
      float hg = *(const float*)swzp(GO, row, 4 * (384 + e2), 2048);
      float ng = ftanh(ig + rr * hg + bovl[240 + e2]);
      float* hp = (float*)swzp(hcf, row, 4 * (16 + e2), 640);
      float ho = *hp;
      float v = ng + zz * (ho - ng);
      *hp = v;
      *(f16*)swzp(XA, row, 2 * (16 + e2), 512) = (f16)v;
    }
    if (tid < 256) {
      int row = tid >> 4, t = tid & 15;
      float ixr = G2[row * 96 + t], ixi = G2[row * 96 + 16 + t], ixn = G2[row * 96 + 32 + t];
      float hhr = G2[row * 96 + 48 + t], hhi = G2[row * 96 + 64 + t], hhn = G2[row * 96 + 80 + t];
      float br = bdvl[t], bi = bdvl[16 + t], bn = bdvl[32 + t];
      float rr = fsigm(br * ixr * hhr);
      float zz = fsigm(bi * ixi * hhi);
      float sp = bn * ixn * rr * hhn;
      float ng = (sp > 20.f) ? sp : __logf(1.f + __expf(sp));
      float* hp = (float*)swzp(hcf, row, 4 * t, 640);
      float v = zz * (*hp) + (1.f - zz) * __logf(ng);
      *hp = v;
      *(f16*)swzp(XA, row, 2 * t, 512) = (f16)v;
    }
    __syncthreads();
  }

  // ---- classifier ----
  if (tid < 80) {
    int row = tid / 5, c = tid - row * 5;
    float a = cbv[c];
    for (int k = 0; k < 136; ++k)
      a += *(const float*)swzp(hcf, row, 4 * k, 640) * cw[k * 5 + c];
    out[(size_t)(blk * 16 + row) * 5 + c] = a;
  }
}

// ------------------------------ launch ------------------------------
extern "C" void kernel_launch(void* const* d_in, const int* in_sizes, int n_in,
                              void* d_out, int out_size, void* d_ws, size_t ws_size,
                              hipStream_t stream) {
  const float* x       = (const float*)d_in[0];
  const float* fw      = (const float*)d_in[1];
  const float* s_tri   = (const float*)d_in[2];
  const float* conv1_w = (const float*)d_in[3];
  const float* conv1_b = (const float*)d_in[4];
  const float* bn1_g   = (const float*)d_in[5];
  const float* bn1_b   = (const float*)d_in[6];
  const float* conv2_w = (const float*)d_in[7];
  const float* conv2_b = (const float*)d_in[8];
  const float* bn2_g   = (const float*)d_in[9];
  const float* bn2_b   = (const float*)d_in[10];
  const float* wx_d    = (const float*)d_in[11];
  const float* wh_d    = (const float*)d_in[12];
  const float* bias_d  = (const float*)d_in[13];
  const float* wx_o    = (const float*)d_in[14];
  const float* wh_o    = (const float*)d_in[15];
  const float* bias_o  = (const float*)d_in[16];
  const float* ode_w0  = (const float*)d_in[17];
  const float* ode_b0  = (const float*)d_in[18];
  const float* ode_w1  = (const float*)d_in[19];
  const float* ode_b1  = (const float*)d_in[20];
  const float* ode_w2  = (const float*)d_in[21];
  const float* ode_b2  = (const float*)d_in[22];
  const float* ode_w3  = (const float*)d_in[23];
  const float* ode_b3  = (const float*)d_in[24];
  const float* cls_w   = (const float*)d_in[25];
  const float* cls_b   = (const float*)d_in[26];

  float* ws = (float*)d_ws;
  float* h1  = ws;                    // 8,908,800 floats (K1->K2), then dead
  float* h3  = ws;                    // 1,075,200 floats (K4->K6)
  float* xd  = ws + 1075200;          // 51,200
  float* xo  = ws + 1126400;          // 384,000
  float* h2  = ws + 8908800;          // 7,680,000 (K2->K4), then reused by K0
  float* p1  = ws + 16588800;         // 614,400
  float* bn1 = ws + 17203200;         // 192
  float* p2  = ws + 17203392;         // 25,600
  float* bn2 = ws + 17228992;         // 32
  uint32_t* pk = (uint32_t*)(ws + 8908800);  // packed W-fragments (dead h2)

  hipLaunchKernelGGL(k1_fb,   dim3(NIMG),   dim3(256), 0, stream, x, fw, s_tri, h1);
  hipLaunchKernelGGL(k2_conv1,dim3(NIMG/2), dim3(256), 0, stream, h1, conv1_w, conv1_b, h2, p1);
  hipLaunchKernelGGL(k3_bn1,  dim3(96),     dim3(256), 0, stream, p1, bn1_g, bn1_b, bn1);
  hipLaunchKernelGGL(k4_conv2,dim3(NIMG/4), dim3(256), 0, stream, h2, conv2_w, conv2_b, bn1, h3, p2);
  hipLaunchKernelGGL(k5_bn2,  dim3(16),     dim3(256), 0, stream, p2, bn2_g, bn2_b, bn2);
  hipLaunchKernelGGL(k6_oas,  dim3(NIMG/4), dim3(256), 0, stream, h3, bn2, xd, xo);
  hipLaunchKernelGGL(k0_pack, dim3((PK2_TOT + 255) / 256), dim3(256), 0, stream,
                     ode_w0, ode_w1, ode_w2, ode_w3, wx_o, wh_o, pk);
  hipLaunchKernelGGL(k7_scan, dim3(4),      dim3(256), 0, stream,
                     xd, xo, wx_d, wh_d, bias_d, bias_o, pk,
                     ode_b0, ode_b1, ode_b2, ode_b3, cls_w, cls_b, (float*)d_out);
}